// Round 6
// baseline (77.962 us; speedup 1.0000x reference)
//
#include <hip/hip_runtime.h>
#include <hip/hip_bf16.h>

#define BATCH 32
#define NNODE 2048
#define NEDGE 8192
#define DIM   512
#define NREL  8
#define VG    50000
#define VS    25000
#define ZI    4608           // 512 (root) + 8*512 (basis)
#define NCH   36             // 4608 / 128 i-chunks
#define GB6   3125           // 50000/16
#define SB6   1563           // ceil(25000/16)
#define PG    25             // lse chunks for global head (2048 each)
#define PS    13             // lse chunks for sense head
#define WROWB 2064           // padded LDS row stride: 2KB + 16B (bank-even)

typedef __attribute__((ext_vector_type(4))) float f32x4;
typedef __attribute__((ext_vector_type(8))) short s16x8;

// ---------------------------------------------------------------------------
// K1: per-batch edge scan (dst==0 only), builds z[g][0..4607]
// ---------------------------------------------------------------------------
__global__ __launch_bounds__(512) void k_conv(const float* __restrict__ x,
                                              const int* __restrict__ ei,
                                              const int* __restrict__ et,
                                              const float* __restrict__ comp,
                                              float* __restrict__ z) {
    int g = blockIdx.x;
    int t = threadIdx.x;
    int wv = t >> 6, lane = t & 63;
    __shared__ int elds[8 * 128];
    __shared__ int wcnt[8];
    const int* srcp = ei + (size_t)(g * 2 + 0) * NEDGE;
    const int* dstp = ei + (size_t)(g * 2 + 1) * NEDGE;

    int run = 0;
    for (int it = 0; it < 16; it++) {
        int e = wv * 1024 + it * 64 + lane;
        bool m = (dstp[e] == 0);
        unsigned long long mask = __ballot(m);
        int rank = __popcll(mask & ((1ull << lane) - 1ull));
        if (m && (run + rank) < 128) elds[wv * 128 + run + rank] = e;
        run += (int)__popcll(mask);
    }
    if (lane == 0) wcnt[wv] = (run > 128) ? 128 : run;
    __syncthreads();

    int d = t;
    float s0=0,s1=0,s2=0,s3=0,s4=0,s5=0,s6=0,s7=0;
    int   c0=0,c1=0,c2=0,c3=0,c4=0,c5=0,c6=0,c7=0;
    for (int w = 0; w < 8; w++) {
        int cw = wcnt[w];
        for (int i = 0; i < cw; i++) {
            int e = elds[w * 128 + i];
            int r = et[(size_t)g * NEDGE + e];
            int sn = srcp[e];
            float val = x[((size_t)g * NNODE + sn) * DIM + d];
            if (r == 0) { s0 += val; c0++; }
            if (r == 1) { s1 += val; c1++; }
            if (r == 2) { s2 += val; c2++; }
            if (r == 3) { s3 += val; c3++; }
            if (r == 4) { s4 += val; c4++; }
            if (r == 5) { s5 += val; c5++; }
            if (r == 6) { s6 += val; c6++; }
            if (r == 7) { s7 += val; c7++; }
        }
    }
    float sv[8] = {s0,s1,s2,s3,s4,s5,s6,s7};
    float inv[8];
    int   cv[8] = {c0,c1,c2,c3,c4,c5,c6,c7};
    #pragma unroll
    for (int r = 0; r < 8; r++) inv[r] = 1.0f / fmaxf((float)cv[r], 1.0f);

    z[(size_t)g * ZI + d] = x[((size_t)g * NNODE + 0) * DIM + d];
    #pragma unroll
    for (int b = 0; b < 8; b++) {
        float y = 0.f;
        #pragma unroll
        for (int r = 0; r < 8; r++) y += comp[r * 8 + b] * inv[r] * sv[r];
        z[(size_t)g * ZI + 512 + b * 512 + d] = y;
    }
}

// ---------------------------------------------------------------------------
// K2a: partial GEMM  part2[c][g][d] = sum_{i in chunk c} z[g][i] * M[i][d]
// ---------------------------------------------------------------------------
__global__ __launch_bounds__(512) void k_gemm_part(const float* __restrict__ z,
                                                   const float* __restrict__ root,
                                                   const float* __restrict__ basis,
                                                   float* __restrict__ part2) {
    int bx = blockIdx.x;
    int dt = bx & 3;
    int cc = bx >> 2;
    int t = threadIdx.x;
    int dl = t & 127, gq = t >> 7;
    __shared__ float ztT[128][33];
    #pragma unroll
    for (int rep = 0; rep < 8; rep++) {
        int flat = rep * 512 + t;
        int g = flat >> 7, i = flat & 127;
        ztT[i][g] = z[(size_t)g * ZI + cc * 128 + i];
    }
    __syncthreads();
    const float* M = (cc < 4) ? (root + (size_t)(cc * 128) * 512)
                              : (basis + (size_t)((cc - 4) * 128) * 512);
    float acc[8] = {0,0,0,0,0,0,0,0};
    for (int i = 0; i < 128; i++) {
        float m = M[(size_t)i * 512 + dt * 128 + dl];
        #pragma unroll
        for (int j = 0; j < 8; j++) acc[j] += ztT[i][gq * 8 + j] * m;
    }
    #pragma unroll
    for (int j = 0; j < 8; j++) {
        int g = gq * 8 + j;
        part2[((size_t)cc * 32 + g) * 512 + dt * 128 + dl] = acc[j];
    }
}

// ---------------------------------------------------------------------------
// K2b: h0 reduce + relu + pack bf16 pairs.  h0t[g*256 + p] = bf16(2p)|bf16(2p+1)<<16
// ---------------------------------------------------------------------------
__device__ __forceinline__ unsigned bf16rne(float f) {
    unsigned u = __float_as_uint(f);
    return (u + 0x7FFFu + ((u >> 16) & 1u)) >> 16;
}

__global__ __launch_bounds__(256) void k_h0(const float* __restrict__ part2,
                                            const float* __restrict__ bias_conv,
                                            unsigned* __restrict__ h0t) {
    int g = blockIdx.x;
    int p = threadIdx.x;          // pair index kp = 0..255
    int d0 = 2 * p;
    float v0 = bias_conv[d0], v1 = bias_conv[d0 + 1];
    for (int cc = 0; cc < NCH; cc++) {
        const float* pp = part2 + ((size_t)cc * 32 + g) * 512 + d0;
        v0 += pp[0];
        v1 += pp[1];
    }
    v0 = fmaxf(v0, 0.f);
    v1 = fmaxf(v1, 0.f);
    h0t[g * 256 + p] = bf16rne(v0) | (bf16rne(v1) << 16);
}

// ---------------------------------------------------------------------------
// K3 v6: contiguous-stream MFMA GEMV.  logits[g][v] = bias[v] + dot(h0[g],w[v]).
// Block = 256 thr (4 waves), tile = 16 vocab rows x K=512 (one contiguous
// 32KB global region). Every global_load_lds instruction is a fully
// lane-ascending 1KB half-row (NO address swizzle -> full DMA coalescing).
// LDS W layout: [16 rows][2064B] - the 16B row-pad makes the strided
// ds_read_b128 B-fragment reads bank-EVEN (stride 516 words == 4 mod 32).
// Waves split K 4-ways (4 kc each), partial accs reduced via 8KB LDS.
// LDS 32KB h0 + 33KB W + 8KB red = 74KB -> 2 blocks/CU; latency hidden by
// co-resident block + 4688-block grid pipelining.
// ---------------------------------------------------------------------------
__device__ __forceinline__ void gload_lds16(const float* gsrc, float* ldst) {
    __builtin_amdgcn_global_load_lds(
        (const __attribute__((address_space(1))) void*)gsrc,
        (__attribute__((address_space(3))) void*)ldst,
        16, 0, 0);
}

__device__ __forceinline__ short f2bf(float f) {
    __hip_bfloat16 h = __float2bfloat16(f);
    return *reinterpret_cast<short*>(&h);
}

__global__ __launch_bounds__(256, 2) void k_logits6(const unsigned* __restrict__ h0t,
                                                    const float* __restrict__ wg,
                                                    const float* __restrict__ bg,
                                                    const float* __restrict__ wsn,
                                                    const float* __restrict__ bsv,
                                                    float* __restrict__ out) {
    __shared__ __align__(16) unsigned char hlds[32768];        // h0 [32 g][1KB], 16B-XOR
    __shared__ __align__(16) unsigned char wlds[16 * WROWB];   // W [16 rows][2064B]
    __shared__ __align__(16) float redbuf[2048];               // [4 kw][2 grp][16 col][16 row]

    int t = threadIdx.x;
    int bx = blockIdx.x;
    int wv = t >> 6, l = t & 63;

    const float* w; const float* bias; float* ob; int V; int v0;
    if (bx < GB6) { w = wg;  bias = bg;  ob = out;                      V = VG; v0 = bx * 16; }
    else          { w = wsn; bias = bsv; ob = out + (size_t)BATCH * VG; V = VS; v0 = (bx - GB6) * 16; }
    int Vm1 = V - 1;

    // ---- W staging: 32 wave-instructions, each a contiguous 1KB half-row ----
    #pragma unroll
    for (int j = 0; j < 8; j++) {
        int i   = wv * 8 + j;          // block instr 0..31 (wave-uniform)
        int row = i >> 1;              // tile row 0..15
        int kh  = i & 1;               // k-half
        int vr  = v0 + row; if (vr > Vm1) vr = Vm1;
        const float* src = w + (size_t)vr * 512 + kh * 256 + l * 4;
        gload_lds16(src, (float*)&wlds[row * WROWB + kh * 1024]);
    }

    // ---- h0 -> LDS (16B-granule XOR by batch row), same scheme as v5 ----
    #pragma unroll
    for (int rep = 0; rep < 8; rep++) {
        int idx = rep * 256 + t;               // uint4 index, 2048 total
        int g = idx >> 6, q = idx & 63;
        uint4 val = *(const uint4*)&h0t[idx * 4];
        *(uint4*)&hlds[g * 1024 + ((q ^ (g & 7)) << 4)] = val;
    }
    __syncthreads();   // drains vmcnt(0)+lgkmcnt(0): W and h0 resident

    // ---- compute: wave wv handles kc = 4wv..4wv+3 ----
    int c  = l & 15;          // vocab col within tile AND h0 batch row
    int kg = l >> 4;          // k-group 0..3
    int swz = c & 7;
    const unsigned char* ha = &hlds[c * 1024];
    const unsigned char* hb = &hlds[(c + 16) * 1024];

    f32x4 acc0 = {0.f, 0.f, 0.f, 0.f};
    f32x4 acc1 = {0.f, 0.f, 0.f, 0.f};

    #pragma unroll
    for (int j = 0; j < 4; j++) {
        int kc = wv * 4 + j;
        int gr = ((kc * 4 + kg) ^ swz) << 4;
        s16x8 a0 = *(const s16x8*)(ha + gr);
        s16x8 a1 = *(const s16x8*)(hb + gr);
        const float4* bp = (const float4*)&wlds[c * WROWB + kc * 128 + kg * 32];
        float4 b0 = bp[0];
        float4 b1 = bp[1];
        s16x8 bf;
        bf[0] = f2bf(b0.x); bf[1] = f2bf(b0.y); bf[2] = f2bf(b0.z); bf[3] = f2bf(b0.w);
        bf[4] = f2bf(b1.x); bf[5] = f2bf(b1.y); bf[6] = f2bf(b1.z); bf[7] = f2bf(b1.w);
        acc0 = __builtin_amdgcn_mfma_f32_16x16x32_bf16(a0, bf, acc0, 0, 0, 0);
        acc1 = __builtin_amdgcn_mfma_f32_16x16x32_bf16(a1, bf, acc1, 0, 0, 0);
    }

    // ---- partials to LDS: redbuf[kw][grp][col][row], b128 per store ----
    {
        float* rb = redbuf + wv * 512;
        int ro = c * 16 + kg * 4;
        *(f32x4*)&rb[ro]       = acc0;
        *(f32x4*)&rb[256 + ro] = acc1;
    }
    __syncthreads();

    // ---- final combine + bias + store ----
    {
        int grp = t >> 7;
        int cc  = (t & 127) >> 3;
        int r2  = (t & 7) * 2;
        float s0 = 0.f, s1 = 0.f;
        #pragma unroll
        for (int kw = 0; kw < 4; kw++) {
            int base = kw * 512 + grp * 256 + cc * 16 + r2;
            s0 += redbuf[base];
            s1 += redbuf[base + 1];
        }
        int vv = v0 + cc;
        if (vv < V) {
            float bia = bias[vv];
            int g = grp * 16 + r2;
            ob[(size_t)g * V + vv]       = s0 + bia;
            ob[(size_t)(g + 1) * V + vv] = s1 + bia;
        }
    }
}

// ---------------------------------------------------------------------------
// K4: log-softmax pieces
// ---------------------------------------------------------------------------
__global__ __launch_bounds__(256) void k_lse_part(const float* __restrict__ out,
                                                  float* __restrict__ part) {
    int bx = blockIdx.x;
    int V, ci, pidx;
    const float* row;
    if (bx < 32 * PG) {
        int g = bx / PG; ci = bx % PG; V = VG;
        row = out + (size_t)g * VG;
        pidx = g * PG + ci;
    } else {
        int b2 = bx - 32 * PG;
        int g = b2 / PS; ci = b2 % PS; V = VS;
        row = out + (size_t)BATCH * VG + (size_t)g * VS;
        pidx = 32 * PG + g * PS + ci;
    }
    int t = threadIdx.x;
    float p = 0.f;
    int base = ci * 2048 + t * 8;
    #pragma unroll
    for (int jj = 0; jj < 8; jj++) {
        int idx = base + jj;
        if (idx < V) p += expf(row[idx]);
    }
    #pragma unroll
    for (int s = 1; s < 64; s <<= 1) p += __shfl_xor(p, s);
    __shared__ float wsum[4];
    if ((t & 63) == 0) wsum[t >> 6] = p;
    __syncthreads();
    if (t == 0) part[pidx] = wsum[0] + wsum[1] + wsum[2] + wsum[3];
}

__global__ __launch_bounds__(64) void k_lse_final(const float* __restrict__ part,
                                                  float* __restrict__ lse) {
    int t = threadIdx.x;
    int head = t >> 5, g = t & 31;
    float s = 0.f;
    if (head == 0) { for (int c = 0; c < PG; c++) s += part[g * PG + c]; }
    else           { for (int c = 0; c < PS; c++) s += part[32 * PG + g * PS + c]; }
    lse[t] = logf(s);
}

__global__ __launch_bounds__(256) void k_sub(float* __restrict__ out,
                                             const float* __restrict__ lse) {
    unsigned i4 = blockIdx.x * 256u + threadIdx.x;
    if (i4 >= 600000u) return;
    unsigned idx = i4 * 4u;
    float l;
    if (idx < 1600000u) l = lse[idx / 50000u];
    else                l = lse[32u + (idx - 1600000u) / 25000u];
    float4 v = *(float4*)(out + idx);
    v.x -= l; v.y -= l; v.z -= l; v.w -= l;
    *(float4*)(out + idx) = v;
}

// ---------------------------------------------------------------------------
extern "C" void kernel_launch(void* const* d_in, const int* in_sizes, int n_in,
                              void* d_out, int out_size, void* d_ws, size_t ws_size,
                              hipStream_t stream) {
    const float* x        = (const float*)d_in[0];
    const int*   ei       = (const int*)  d_in[1];
    const int*   et       = (const int*)  d_in[2];
    const float* basis    = (const float*)d_in[3];
    const float* comp     = (const float*)d_in[4];
    const float* root     = (const float*)d_in[5];
    const float* biasc    = (const float*)d_in[6];
    const float* wg       = (const float*)d_in[7];
    const float* bg       = (const float*)d_in[8];
    const float* wsn      = (const float*)d_in[9];
    const float* bsv      = (const float*)d_in[10];
    float* out = (float*)d_out;

    float* z     = out;
    float* part2 = out + (size_t)BATCH * ZI;
    unsigned* h0t  = (unsigned*)d_ws;            // 8192 uints = 32KB
    float*    plse = (float*)d_ws + 8192;
    float*    lse  = plse + 32 * PG + 32 * PS;

    k_conv     <<<BATCH, 512, 0, stream>>>(x, ei, et, comp, z);
    k_gemm_part<<<NCH * 4, 512, 0, stream>>>(z, root, basis, part2);
    k_h0       <<<BATCH, 256, 0, stream>>>(part2, biasc, h0t);
    k_logits6  <<<GB6 + SB6, 256, 0, stream>>>(h0t, wg, bg, wsn, bsv, out);
    k_lse_part <<<32 * PG + 32 * PS, 256, 0, stream>>>(out, plse);
    k_lse_final<<<1, 64, 0, stream>>>(plse, lse);
    k_sub      <<<2344, 256, 0, stream>>>(out, lse);
}